// Round 13
// baseline (536.694 us; speedup 1.0000x reference)
//
#include <hip/hip_runtime.h>
#include <cstdint>
#include <cstddef>

#define NN 250000   // nodes
#define FF 256      // channels
#define GG 4096     // graphs
#define TT 6        // processing steps
#define GPB 16      // graphs per block in steps_kernel
#define SBLK (GG / GPB)   // 256 blocks

typedef _Float16 half8_t __attribute__((ext_vector_type(8)));
typedef _Float16 half4_t __attribute__((ext_vector_type(4)));
typedef _Float16 half2_t __attribute__((ext_vector_type(2)));
typedef float f32x4 __attribute__((ext_vector_type(4)));

__device__ __forceinline__ float fdot2f(half2_t a, half2_t b, float c) {
#if __has_builtin(__builtin_amdgcn_fdot2)
  return __builtin_amdgcn_fdot2(a, b, c, false);
#else
  return c + (float)a[0] * (float)b[0] + (float)a[1] * (float)b[1];
#endif
}

__device__ __forceinline__ float dot8acc(half8_t x, half8_t q, float acc) {
  acc = fdot2f((half2_t){x[0], x[1]}, (half2_t){q[0], q[1]}, acc);
  acc = fdot2f((half2_t){x[2], x[3]}, (half2_t){q[2], q[3]}, acc);
  acc = fdot2f((half2_t){x[4], x[5]}, (half2_t){q[4], q[5]}, acc);
  acc = fdot2f((half2_t){x[6], x[7]}, (half2_t){q[6], q[7]}, acc);
  return acc;
}

// ---------------- t=0: fused prep + bias-LSTM + f32 sweep + x16 mirror ----------------
// (unchanged from R11/R12 — near its HBM-compulsory floor)
__global__ __launch_bounds__(256) void attn0_kernel(
    const float* __restrict__ x32, const int* __restrict__ batch,
    const float* __restrict__ Wih, const float* __restrict__ Whh,
    const float* __restrict__ bih, const float* __restrict__ bhh,
    _Float16* __restrict__ w16f, int* __restrict__ starts,
    _Float16* __restrict__ x16w, _Float16* __restrict__ q16out) {
  int g = blockIdx.x, tid = threadIdx.x, lane = tid & 63, w = tid >> 6;
  __shared__ int sgs[2];
  __shared__ __align__(16) float h_sh[FF];
  __shared__ __align__(16) float rw[4][FF];
  __shared__ float mw[4], sw[4];

  if (tid < 2) {
    int target = g + tid;
    int lo = 0;
    if (target >= GG) lo = NN;
    else {
      int hi = NN;
      while (lo < hi) {
        int mid = (lo + hi) >> 1;
        if (batch[mid] < target) lo = mid + 1; else hi = mid;
      }
    }
    sgs[tid] = lo;
    starts[g + tid] = lo;
  }

  // w16f prep: blocks 0..511 x 1024 elements = 524288 exactly.
  if (g < 512) {
#pragma unroll
    for (int e = 0; e < 4; ++e) {
      int idx = g * 1024 + e * 256 + tid;
      int n = idx >> 9, k = idx & 511;
      float v = Wih[(size_t)n * 512 + k];
      if (k < FF) v += Whh[(size_t)n * FF + k];
      int dest = ((n >> 4) * 16 + (k >> 5)) * 512 + ((k >> 3) & 3) * 128 +
                 (n & 15) * 8 + (k & 7);
      w16f[dest] = (_Float16)v;
    }
  }

  float bi = bih[tid] + bhh[tid];
  float bg = bih[tid + 512] + bhh[tid + 512];
  float bo = bih[tid + 768] + bhh[tid + 768];
  float si0 = 1.f / (1.f + __expf(-bi));
  float so0 = 1.f / (1.f + __expf(-bo));
  float cv0 = si0 * tanhf(bg);
  float hv0 = so0 * tanhf(cv0);
  q16out[(size_t)g * 512 + tid] = (_Float16)hv0;
  h_sh[tid] = hv0;
  __syncthreads();

  f32x4 qv = *(const f32x4*)&h_sh[4 * lane];
  int s0 = sgs[0], cnt = sgs[1] - sgs[0];

  float m = -INFINITY, ssum = 0.f;
  f32x4 racc = {0.f, 0.f, 0.f, 0.f};
  for (int i0 = w * 4; i0 < cnt; i0 += 16) {
    f32x4 xv[4];
    float d[4];
    bool vld[4];
#pragma unroll
    for (int j = 0; j < 4; ++j) {
      int idx = i0 + j;
      vld[j] = idx < cnt;
      int node = vld[j] ? idx : cnt - 1;
      xv[j] = __builtin_nontemporal_load(
          (const f32x4*)(x32 + (size_t)(s0 + node) * FF + 4 * lane));
    }
#pragma unroll
    for (int j = 0; j < 4; ++j) {
      half4_t hx;
      hx[0] = (_Float16)xv[j][0]; hx[1] = (_Float16)xv[j][1];
      hx[2] = (_Float16)xv[j][2]; hx[3] = (_Float16)xv[j][3];
      int node = vld[j] ? (i0 + j) : cnt - 1;
      *(half4_t*)(x16w + (size_t)(s0 + node) * FF + 4 * lane) = hx;
    }
#pragma unroll
    for (int j = 0; j < 4; ++j)
      d[j] = xv[j][0] * qv[0] + xv[j][1] * qv[1] + xv[j][2] * qv[2] + xv[j][3] * qv[3];
#pragma unroll
    for (int off = 32; off; off >>= 1)
#pragma unroll
      for (int j = 0; j < 4; ++j) d[j] += __shfl_xor(d[j], off);
#pragma unroll
    for (int j = 0; j < 4; ++j) if (!vld[j]) d[j] = -INFINITY;
    float gm = fmaxf(fmaxf(d[0], d[1]), fmaxf(d[2], d[3]));
    if (gm > m) {
      float sc = __expf(m - gm);
      ssum *= sc; racc *= sc;
      m = gm;
    }
#pragma unroll
    for (int j = 0; j < 4; ++j) {
      float p = __expf(d[j] - m);
      ssum += p;
      racc += p * xv[j];
    }
  }

  if (lane == 0) { mw[w] = m; sw[w] = ssum; }
  *(f32x4*)&rw[w][4 * lane] = racc;
  __syncthreads();
  float M = fmaxf(fmaxf(mw[0], mw[1]), fmaxf(mw[2], mw[3]));
  float e0 = (mw[0] == -INFINITY) ? 0.f : __expf(mw[0] - M);
  float e1 = (mw[1] == -INFINITY) ? 0.f : __expf(mw[1] - M);
  float e2 = (mw[2] == -INFINITY) ? 0.f : __expf(mw[2] - M);
  float e3 = (mw[3] == -INFINITY) ? 0.f : __expf(mw[3] - M);
  float denom = sw[0] * e0 + sw[1] * e1 + sw[2] * e2 + sw[3] * e3;
  float rs = rw[0][tid] * e0 + rw[1][tid] * e1 + rw[2][tid] * e2 + rw[3][tid] * e3;
  float r = rs / (denom + 1e-16f);
  if (cnt == 0) r = 0.f;
  q16out[(size_t)g * 512 + FF + tid] = (_Float16)r;
}

// ---------------- t=1..5: all remaining steps, 16 waves/block ----------------
// Attention rebuilt around node-per-lane dots (R12 counters: VALUBusy pinned
// at 34% while occupancy doubled -> DS/shuffle pipe saturation; per-node
// shuffle trees eliminated: 12 shuffles per 64-node chunk instead of ~224).
__global__ __launch_bounds__(1024, 1) void steps_kernel(
    const _Float16* __restrict__ x16, const _Float16* __restrict__ w16f,
    const _Float16* __restrict__ q16a, const int* __restrict__ starts,
    const float* __restrict__ bih, const float* __restrict__ bhh,
    float* __restrict__ qstar) {
  int tid = threadIdx.x, lane = tid & 63, w = tid >> 6;   // w in 0..15
  int lr = lane & 15, kq = lane >> 4;     // gemm quarter coords
  int sl = lane & 31, hf = lane >> 5;     // attn half coords
  int g0 = blockIdx.x * GPB;

  __shared__ _Float16 qs[GPB][520];       // q_star rows (520 = 512 + 8 pad)
  __shared__ float cst[GPB][256];         // LSTM cell state
  __shared__ float pbuf[GPB][64];         // per-chunk softmax weights
  __shared__ int sgs[GPB + 1];

  // ---- init ----
  if (tid <= GPB) sgs[tid] = starts[g0 + tid];
  {
    int i = tid >> 6, c8 = tid & 63;
    *(half8_t*)&qs[i][c8 * 8] =
        *(const half8_t*)(q16a + (size_t)(g0 + i) * 512 + c8 * 8);
  }
  {
    int f = tid & 255;
    float bi = bih[f] + bhh[f];
    float bg = bih[f + 512] + bhh[f + 512];
    float si0 = 1.f / (1.f + __expf(-bi));
    float cv0 = si0 * tanhf(bg);
    for (int i = tid >> 8; i < GPB; i += 4) cst[i][f] = cv0;
  }
  int f = w * 16 + lr;
  float bi_ = bih[f] + bhh[f];
  float bf_ = bih[f + 256] + bhh[f + 256];
  float bg_ = bih[f + 512] + bhh[f + 512];
  float bo_ = bih[f + 768] + bhh[f + 768];
  __syncthreads();

  for (int t = 1; t < TT; ++t) {
    bool last = (t == TT - 1);

    // ---- gemm: 16 graphs x 16 f-cols x 4 gates, K = 512 (unchanged) ----
    f32x4 acc[4];
#pragma unroll
    for (int gt = 0; gt < 4; ++gt) acc[gt] = (f32x4){0.f, 0.f, 0.f, 0.f};

#pragma unroll 4
    for (int ks = 0; ks < 16; ++ks) {
      int kk = ks * 32 + kq * 8;
      half8_t a = *(const half8_t*)&qs[lr][kk];
#pragma unroll
      for (int gt = 0; gt < 4; ++gt) {
        int nf = gt * 16 + w;
        half8_t b = *(const half8_t*)(
            w16f + ((size_t)nf * 16 + ks) * 512 + lane * 8);
        acc[gt] = __builtin_amdgcn_mfma_f32_16x16x32_f16(a, b, acc[gt], 0, 0, 0);
      }
    }
    __syncthreads();

    // ---- LSTM pointwise (unchanged) ----
#pragma unroll
    for (int r = 0; r < 4; ++r) {
      int gl = kq * 4 + r;
      float ig = acc[0][r] + bi_;
      float fg = acc[1][r] + bf_;
      float gv = acc[2][r] + bg_;
      float og = acc[3][r] + bo_;
      float si = 1.f / (1.f + __expf(-ig));
      float sf = 1.f / (1.f + __expf(-fg));
      float so = 1.f / (1.f + __expf(-og));
      float cv = sf * cst[gl][f] + si * tanhf(gv);
      float hv = so * tanhf(cv);
      cst[gl][f] = cv;
      qs[gl][f] = (_Float16)hv;
      if (last) qstar[(size_t)(g0 + gl) * 512 + f] = hv;
    }
    __syncthreads();

    // ---- attention: wave w owns graph w; node-per-lane dot phase ----
    {
      int ii = w;
      int s0 = sgs[ii];
      int cnt = sgs[ii + 1] - s0;

      float m = -INFINITY, ssum = 0.f;
      float racc[8];
#pragma unroll
      for (int e = 0; e < 8; ++e) racc[e] = 0.f;

      for (int base = 0; base < cnt; base += 64) {
        // -- dot phase: lane owns node base+lane; q via uniform LDS reads --
        int node = base + lane;
        bool v = node < cnt;
        const _Float16* row = x16 + (size_t)(s0 + (v ? node : cnt - 1)) * FF;
        float d0 = 0.f, d1 = 0.f, d2 = 0.f, d3 = 0.f;
#pragma unroll
        for (int c = 0; c < 32; c += 4) {   // 4 chains, 4 loads in flight
          half8_t x0 = *(const half8_t*)(row + (c + 0) * 8);
          half8_t x1 = *(const half8_t*)(row + (c + 1) * 8);
          half8_t x2 = *(const half8_t*)(row + (c + 2) * 8);
          half8_t x3 = *(const half8_t*)(row + (c + 3) * 8);
          half8_t q0 = *(const half8_t*)&qs[ii][(c + 0) * 8];  // broadcast
          half8_t q1 = *(const half8_t*)&qs[ii][(c + 1) * 8];
          half8_t q2 = *(const half8_t*)&qs[ii][(c + 2) * 8];
          half8_t q3 = *(const half8_t*)&qs[ii][(c + 3) * 8];
          d0 = dot8acc(x0, q0, d0);
          d1 = dot8acc(x1, q1, d1);
          d2 = dot8acc(x2, q2, d2);
          d3 = dot8acc(x3, q3, d3);
        }
        float e = (d0 + d1) + (d2 + d3);
        if (!v) e = -INFINITY;

        // -- chunk softmax: ONE max tree + ONE sum tree per 64 nodes --
        float cm = e;
#pragma unroll
        for (int off = 32; off; off >>= 1) cm = fmaxf(cm, __shfl_xor(cm, off));
        if (cm > m) {                        // wave-uniform
          float sc = __expf(m - cm);
          ssum *= sc;
#pragma unroll
          for (int e2 = 0; e2 < 8; ++e2) racc[e2] *= sc;
          m = cm;
        }
        float p = __expf(e - m);             // invalid lanes: exp(-inf)=0
        float cs = p;
#pragma unroll
        for (int off = 32; off; off >>= 1) cs += __shfl_xor(cs, off);
        ssum += cs;
        pbuf[ii][lane] = p;                  // wave-private, no barrier

        // -- weighted pass: channel-parallel, 2 nodes/iter, p via LDS --
        int lim = cnt - base; if (lim > 64) lim = 64;
        for (int i = 0; i < lim; i += 2) {
          int j = i + hf;                    // hf in {0,1}
          bool jv = j < lim;
          float pj = pbuf[ii][jv ? j : 0];   // 2-addr broadcast read
          if (!jv) pj = 0.f;
          half8_t hx = *(const half8_t*)(
              x16 + (size_t)(s0 + base + (jv ? j : 0)) * FF + sl * 8);
#pragma unroll
          for (int e2 = 0; e2 < 8; ++e2) racc[e2] += pj * (float)hx[e2];
        }
      }

      // combine the two 32-lane halves (8 shuffles, once per graph)
#pragma unroll
      for (int e2 = 0; e2 < 8; ++e2) racc[e2] += __shfl_xor(racc[e2], 32);
      float inv = 1.0f / (ssum + 1e-16f);

      if (hf == 0) {
        half8_t rh;
        float rv[8];
#pragma unroll
        for (int e2 = 0; e2 < 8; ++e2) {
          rv[e2] = (cnt == 0) ? 0.f : racc[e2] * inv;
          rh[e2] = (_Float16)rv[e2];
        }
        *(half8_t*)&qs[ii][256 + sl * 8] = rh;
        if (last) {
          f32x4 lo = {rv[0], rv[1], rv[2], rv[3]};
          f32x4 hi = {rv[4], rv[5], rv[6], rv[7]};
          *(f32x4*)(qstar + (size_t)(g0 + ii) * 512 + 256 + sl * 8) = lo;
          *(f32x4*)(qstar + (size_t)(g0 + ii) * 512 + 260 + sl * 8) = hi;
        }
      }
    }
    __syncthreads();
  }
}

// ---------------- launcher ----------------
extern "C" void kernel_launch(void* const* d_in, const int* in_sizes, int n_in,
                              void* d_out, int out_size, void* d_ws, size_t ws_size,
                              hipStream_t stream) {
  const float* x   = (const float*)d_in[0];
  const int* batch = (const int*)d_in[1];
  // d_in[2] = size (4096), hard-coded
  const float* Wih = (const float*)d_in[3];
  const float* Whh = (const float*)d_in[4];
  const float* bih = (const float*)d_in[5];
  const float* bhh = (const float*)d_in[6];
  float* qstar = (float*)d_out;  // [GG, 512]; steps_kernel t=5 writes it

  uint8_t* p = (uint8_t*)d_ws;
  auto alloc = [&](size_t bytes) {
    uint8_t* q = p;
    p += (bytes + 255) & ~(size_t)255;
    return q;
  };
  _Float16* q16a = (_Float16*)alloc((size_t)GG * 2 * FF * 2);     // 4 MB
  _Float16* w16f = (_Float16*)alloc((size_t)4 * FF * 2 * FF * 2); // 1 MB
  int* starts    = (int*)alloc((size_t)(GG + 1) * 4);
  _Float16* x16  = (_Float16*)alloc((size_t)NN * FF * 2);         // 128 MB

  attn0_kernel<<<GG, 256, 0, stream>>>(
      x, batch, Wih, Whh, bih, bhh, w16f, starts, x16, q16a);

  steps_kernel<<<SBLK, 1024, 0, stream>>>(
      x16, w16f, q16a, starts, bih, bhh, qstar);
}

// Round 14
// 408.606 us; speedup vs baseline: 1.3135x; 1.3135x over previous
//
#include <hip/hip_runtime.h>
#include <cstdint>
#include <cstddef>

#define NN 250000   // nodes
#define FF 256      // channels
#define GG 4096     // graphs
#define TT 6        // processing steps
#define GPB 8       // graphs per block in steps_kernel
#define SBLK (GG / GPB)   // 512 blocks = 2/CU

typedef _Float16 half8_t __attribute__((ext_vector_type(8)));
typedef _Float16 half4_t __attribute__((ext_vector_type(4)));
typedef _Float16 half2_t __attribute__((ext_vector_type(2)));
typedef float f32x4 __attribute__((ext_vector_type(4)));

__device__ __forceinline__ float fdot2f(half2_t a, half2_t b, float c) {
#if __has_builtin(__builtin_amdgcn_fdot2)
  return __builtin_amdgcn_fdot2(a, b, c, false);
#else
  return c + (float)a[0] * (float)b[0] + (float)a[1] * (float)b[1];
#endif
}

__device__ __forceinline__ float dot8(half8_t x, half8_t q) {
  float d = fdot2f((half2_t){x[0], x[1]}, (half2_t){q[0], q[1]}, 0.f);
  d = fdot2f((half2_t){x[2], x[3]}, (half2_t){q[2], q[3]}, d);
  d = fdot2f((half2_t){x[4], x[5]}, (half2_t){q[4], q[5]}, d);
  d = fdot2f((half2_t){x[6], x[7]}, (half2_t){q[6], q[7]}, d);
  return d;
}

// ---------------- t=0: fused prep + bias-LSTM + f32 sweep + x16 mirror ----------------
// (unchanged — at its HBM-compulsory floor ~55 us)
__global__ __launch_bounds__(256) void attn0_kernel(
    const float* __restrict__ x32, const int* __restrict__ batch,
    const float* __restrict__ Wih, const float* __restrict__ Whh,
    const float* __restrict__ bih, const float* __restrict__ bhh,
    _Float16* __restrict__ w16f, int* __restrict__ starts,
    _Float16* __restrict__ x16w, _Float16* __restrict__ q16out) {
  int g = blockIdx.x, tid = threadIdx.x, lane = tid & 63, w = tid >> 6;
  __shared__ int sgs[2];
  __shared__ __align__(16) float h_sh[FF];
  __shared__ __align__(16) float rw[4][FF];
  __shared__ float mw[4], sw[4];

  if (tid < 2) {
    int target = g + tid;
    int lo = 0;
    if (target >= GG) lo = NN;
    else {
      int hi = NN;
      while (lo < hi) {
        int mid = (lo + hi) >> 1;
        if (batch[mid] < target) lo = mid + 1; else hi = mid;
      }
    }
    sgs[tid] = lo;
    starts[g + tid] = lo;
  }

  // w16f prep: blocks 0..511 x 1024 elements = 524288 exactly.
  if (g < 512) {
#pragma unroll
    for (int e = 0; e < 4; ++e) {
      int idx = g * 1024 + e * 256 + tid;
      int n = idx >> 9, k = idx & 511;
      float v = Wih[(size_t)n * 512 + k];
      if (k < FF) v += Whh[(size_t)n * FF + k];
      int dest = ((n >> 4) * 16 + (k >> 5)) * 512 + ((k >> 3) & 3) * 128 +
                 (n & 15) * 8 + (k & 7);
      w16f[dest] = (_Float16)v;
    }
  }

  float bi = bih[tid] + bhh[tid];
  float bg = bih[tid + 512] + bhh[tid + 512];
  float bo = bih[tid + 768] + bhh[tid + 768];
  float si0 = 1.f / (1.f + __expf(-bi));
  float so0 = 1.f / (1.f + __expf(-bo));
  float cv0 = si0 * tanhf(bg);
  float hv0 = so0 * tanhf(cv0);
  q16out[(size_t)g * 512 + tid] = (_Float16)hv0;
  h_sh[tid] = hv0;
  __syncthreads();

  f32x4 qv = *(const f32x4*)&h_sh[4 * lane];
  int s0 = sgs[0], cnt = sgs[1] - sgs[0];

  float m = -INFINITY, ssum = 0.f;
  f32x4 racc = {0.f, 0.f, 0.f, 0.f};
  for (int i0 = w * 4; i0 < cnt; i0 += 16) {
    f32x4 xv[4];
    float d[4];
    bool vld[4];
#pragma unroll
    for (int j = 0; j < 4; ++j) {
      int idx = i0 + j;
      vld[j] = idx < cnt;
      int node = vld[j] ? idx : cnt - 1;
      xv[j] = __builtin_nontemporal_load(
          (const f32x4*)(x32 + (size_t)(s0 + node) * FF + 4 * lane));
    }
#pragma unroll
    for (int j = 0; j < 4; ++j) {
      half4_t hx;
      hx[0] = (_Float16)xv[j][0]; hx[1] = (_Float16)xv[j][1];
      hx[2] = (_Float16)xv[j][2]; hx[3] = (_Float16)xv[j][3];
      int node = vld[j] ? (i0 + j) : cnt - 1;
      *(half4_t*)(x16w + (size_t)(s0 + node) * FF + 4 * lane) = hx;
    }
#pragma unroll
    for (int j = 0; j < 4; ++j)
      d[j] = xv[j][0] * qv[0] + xv[j][1] * qv[1] + xv[j][2] * qv[2] + xv[j][3] * qv[3];
#pragma unroll
    for (int off = 32; off; off >>= 1)
#pragma unroll
      for (int j = 0; j < 4; ++j) d[j] += __shfl_xor(d[j], off);
#pragma unroll
    for (int j = 0; j < 4; ++j) if (!vld[j]) d[j] = -INFINITY;
    float gm = fmaxf(fmaxf(d[0], d[1]), fmaxf(d[2], d[3]));
    if (gm > m) {
      float sc = __expf(m - gm);
      ssum *= sc; racc *= sc;
      m = gm;
    }
#pragma unroll
    for (int j = 0; j < 4; ++j) {
      float p = __expf(d[j] - m);
      ssum += p;
      racc += p * xv[j];
    }
  }

  if (lane == 0) { mw[w] = m; sw[w] = ssum; }
  *(f32x4*)&rw[w][4 * lane] = racc;
  __syncthreads();
  float M = fmaxf(fmaxf(mw[0], mw[1]), fmaxf(mw[2], mw[3]));
  float e0 = (mw[0] == -INFINITY) ? 0.f : __expf(mw[0] - M);
  float e1 = (mw[1] == -INFINITY) ? 0.f : __expf(mw[1] - M);
  float e2 = (mw[2] == -INFINITY) ? 0.f : __expf(mw[2] - M);
  float e3 = (mw[3] == -INFINITY) ? 0.f : __expf(mw[3] - M);
  float denom = sw[0] * e0 + sw[1] * e1 + sw[2] * e2 + sw[3] * e3;
  float rs = rw[0][tid] * e0 + rw[1][tid] * e1 + rw[2][tid] * e2 + rw[3][tid] * e3;
  float r = rs / (denom + 1e-16f);
  if (cnt == 0) r = 0.f;
  q16out[(size_t)g * 512 + FF + tid] = (_Float16)r;
}

// ---------------- t=1..5: GPB=8, 1024 thr, 2 blocks/CU ----------------
// R12's proven channel-parallel attn (coalesced 1 KB bursts; R13's node-per-
// lane scatter tripled FETCH and is reverted). New: 512 blocks -> 2/CU so
// phases of independent blocks overlap and 32 waves/CU issue load bursts.
// Attention: 2 waves per graph (even/odd 16-node chunks) + LDS merge.
__global__ __launch_bounds__(1024, 8) void steps_kernel(
    const _Float16* __restrict__ x16, const _Float16* __restrict__ w16f,
    const _Float16* __restrict__ q16a, const int* __restrict__ starts,
    const float* __restrict__ bih, const float* __restrict__ bhh,
    float* __restrict__ qstar) {
  int tid = threadIdx.x, lane = tid & 63, w = tid >> 6;   // w in 0..15
  int lr = lane & 15, kq = lane >> 4;     // gemm quarter coords
  int sl = lane & 31, hf = lane >> 5;     // attn half coords
  int g0 = blockIdx.x * GPB;

  __shared__ _Float16 qs[16][520];        // rows 0..7 = graphs; 8..15 zero pad
  __shared__ float cst[GPB][256];         // LSTM cell state
  __shared__ float rw[GPB][2][256];       // attn part-merge buffer
  __shared__ float mw[GPB][2], sw[GPB][2];
  __shared__ int sgs[GPB + 1];

  // ---- init ----
  if (tid <= GPB) sgs[tid] = starts[g0 + tid];
  {
    int i = tid >> 6, c8 = tid & 63;      // 1024 threads = 16 rows x 64 chunks
    if (i < GPB)
      *(half8_t*)&qs[i][c8 * 8] =
          *(const half8_t*)(q16a + (size_t)(g0 + i) * 512 + c8 * 8);
    else
      *(half8_t*)&qs[i][c8 * 8] = (half8_t){0, 0, 0, 0, 0, 0, 0, 0};
  }
  {
    int f = tid & 255;
    float bi = bih[f] + bhh[f];
    float bg = bih[f + 512] + bhh[f + 512];
    float si0 = 1.f / (1.f + __expf(-bi));
    float cv0 = si0 * tanhf(bg);
    for (int i = tid >> 8; i < GPB; i += 4) cst[i][f] = cv0;
  }
  int f = w * 16 + lr;                    // wave w owns f-cols [w*16, +16)
  float bi_ = bih[f] + bhh[f];
  float bf_ = bih[f + 256] + bhh[f + 256];
  float bg_ = bih[f + 512] + bhh[f + 512];
  float bo_ = bih[f + 768] + bhh[f + 768];
  __syncthreads();

  for (int t = 1; t < TT; ++t) {
    bool last = (t == TT - 1);

    // ---- gemm: 8 graphs (+8 zero rows) x 16 f-cols x 4 gates, K = 512 ----
    f32x4 acc[4];
#pragma unroll
    for (int gt = 0; gt < 4; ++gt) acc[gt] = (f32x4){0.f, 0.f, 0.f, 0.f};

#pragma unroll 4
    for (int ks = 0; ks < 16; ++ks) {
      int kk = ks * 32 + kq * 8;
      half8_t a = *(const half8_t*)&qs[lr][kk];
#pragma unroll
      for (int gt = 0; gt < 4; ++gt) {
        int nf = gt * 16 + w;
        half8_t b = *(const half8_t*)(
            w16f + ((size_t)nf * 16 + ks) * 512 + lane * 8);
        acc[gt] = __builtin_amdgcn_mfma_f32_16x16x32_f16(a, b, acc[gt], 0, 0, 0);
      }
    }
    __syncthreads();   // all waves done reading qs before h overwrite

    // ---- LSTM pointwise: rows gl < GPB only (kq < 2) ----
#pragma unroll
    for (int r = 0; r < 4; ++r) {
      int gl = kq * 4 + r;
      if (gl < GPB) {
        float ig = acc[0][r] + bi_;
        float fg = acc[1][r] + bf_;
        float gv = acc[2][r] + bg_;
        float og = acc[3][r] + bo_;
        float si = 1.f / (1.f + __expf(-ig));
        float sf = 1.f / (1.f + __expf(-fg));
        float so = 1.f / (1.f + __expf(-og));
        float cv = sf * cst[gl][f] + si * tanhf(gv);
        float hv = so * tanhf(cv);
        cst[gl][f] = cv;
        qs[gl][f] = (_Float16)hv;
        if (last) qstar[(size_t)(g0 + gl) * 512 + f] = hv;
      }
    }
    __syncthreads();   // full h rows visible before attn reads them

    // ---- attention: graph ii = w>>1, part pp = w&1 (even/odd 16-chunks) ----
    {
      int ii = w >> 1, pp = w & 1;
      int s0 = sgs[ii];
      int cnt = sgs[ii + 1] - s0;
      half8_t qh = *(const half8_t*)&qs[ii][sl * 8];

      float m = -INFINITY, ssum = 0.f;
      float racc[8];
#pragma unroll
      for (int e = 0; e < 8; ++e) racc[e] = 0.f;

      for (int i0 = pp * 16; i0 < cnt; i0 += 32) {   // 16 nodes/iter/wave
        half8_t hx[8];
        float d[8];
        bool vld[8];
#pragma unroll
        for (int j = 0; j < 8; ++j) {            // 8 x 1 KB loads in flight
          int idx = i0 + j * 2 + hf;
          vld[j] = idx < cnt;
          int node = vld[j] ? idx : cnt - 1;
          hx[j] = *(const half8_t*)(x16 + (size_t)(s0 + node) * FF + sl * 8);
        }
#pragma unroll
        for (int j = 0; j < 8; ++j) d[j] = dot8(hx[j], qh);
#pragma unroll
        for (int off = 1; off <= 16; off <<= 1)  // 8 interleaved 32-lane trees
#pragma unroll
          for (int j = 0; j < 8; ++j) d[j] += __shfl_xor(d[j], off);
#pragma unroll
        for (int j = 0; j < 8; ++j) if (!vld[j]) d[j] = -INFINITY;
        float gm = -INFINITY;
#pragma unroll
        for (int j = 0; j < 8; ++j) {
          float dother = __shfl_xor(d[j], 32);
          gm = fmaxf(gm, fmaxf(d[j], dother));   // uniform across wave
        }
        if (gm > m) {                            // one rescale per 16 nodes
          float sc = __expf(m - gm);
          ssum *= sc;
#pragma unroll
          for (int e = 0; e < 8; ++e) racc[e] *= sc;
          m = gm;
        }
#pragma unroll
        for (int j = 0; j < 8; ++j) {
          float p = __expf(d[j] - m);            // invalid: exp(-inf)=0
          ssum += p;
#pragma unroll
          for (int e = 0; e < 8; ++e) racc[e] += p * (float)hx[j][e];
        }
      }

      // combine the two 32-lane halves of this wave
      ssum += __shfl_xor(ssum, 32);
#pragma unroll
      for (int e = 0; e < 8; ++e) racc[e] += __shfl_xor(racc[e], 32);

      if (lane == 0) { mw[ii][pp] = m; sw[ii][pp] = ssum; }
      if (hf == 0) {
#pragma unroll
        for (int e = 0; e < 8; ++e) rw[ii][pp][sl * 8 + e] = racc[e];
      }
    }
    __syncthreads();   // both parts' partials visible

    // ---- merge parts (even waves), write r half ----
    if ((w & 1) == 0) {
      int ii = w >> 1;
      int cnt = sgs[ii + 1] - sgs[ii];
      float m0 = mw[ii][0], m1 = mw[ii][1];
      float M = fmaxf(m0, m1);
      float e0 = (m0 == -INFINITY) ? 0.f : __expf(m0 - M);
      float e1 = (m1 == -INFINITY) ? 0.f : __expf(m1 - M);
      float denom = sw[ii][0] * e0 + sw[ii][1] * e1;
      float inv = 1.0f / (denom + 1e-16f);
      if (hf == 0) {
        half8_t rh;
        float rv[8];
#pragma unroll
        for (int e = 0; e < 8; ++e) {
          float v = (rw[ii][0][sl * 8 + e] * e0 + rw[ii][1][sl * 8 + e] * e1) * inv;
          if (cnt == 0) v = 0.f;
          rv[e] = v;
          rh[e] = (_Float16)v;
        }
        *(half8_t*)&qs[ii][256 + sl * 8] = rh;   // r half for next gemm
        if (last) {
          f32x4 lo = {rv[0], rv[1], rv[2], rv[3]};
          f32x4 hi = {rv[4], rv[5], rv[6], rv[7]};
          *(f32x4*)(qstar + (size_t)(g0 + ii) * 512 + 256 + sl * 8) = lo;
          *(f32x4*)(qstar + (size_t)(g0 + ii) * 512 + 260 + sl * 8) = hi;
        }
      }
    }
    __syncthreads();   // r halves written before next step's gemm reads qs
  }
}

// ---------------- launcher ----------------
extern "C" void kernel_launch(void* const* d_in, const int* in_sizes, int n_in,
                              void* d_out, int out_size, void* d_ws, size_t ws_size,
                              hipStream_t stream) {
  const float* x   = (const float*)d_in[0];
  const int* batch = (const int*)d_in[1];
  // d_in[2] = size (4096), hard-coded
  const float* Wih = (const float*)d_in[3];
  const float* Whh = (const float*)d_in[4];
  const float* bih = (const float*)d_in[5];
  const float* bhh = (const float*)d_in[6];
  float* qstar = (float*)d_out;  // [GG, 512]; steps_kernel t=5 writes it

  uint8_t* p = (uint8_t*)d_ws;
  auto alloc = [&](size_t bytes) {
    uint8_t* q = p;
    p += (bytes + 255) & ~(size_t)255;
    return q;
  };
  _Float16* q16a = (_Float16*)alloc((size_t)GG * 2 * FF * 2);     // 4 MB
  _Float16* w16f = (_Float16*)alloc((size_t)4 * FF * 2 * FF * 2); // 1 MB
  int* starts    = (int*)alloc((size_t)(GG + 1) * 4);
  _Float16* x16  = (_Float16*)alloc((size_t)NN * FF * 2);         // 128 MB

  attn0_kernel<<<GG, 256, 0, stream>>>(
      x, batch, Wih, Whh, bih, bhh, w16f, starts, x16, q16a);

  steps_kernel<<<SBLK, 1024, 0, stream>>>(
      x16, w16f, q16a, starts, bih, bhh, qstar);
}

// Round 15
// 303.632 us; speedup vs baseline: 1.7676x; 1.3457x over previous
//
#include <hip/hip_runtime.h>
#include <cstdint>
#include <cstddef>

#define NN 250000   // nodes
#define FF 256      // channels
#define GG 4096     // graphs
#define TT 6        // processing steps
#define GPB 8       // graphs per block in steps_kernel
#define SBLK (GG / GPB)   // 512 blocks

typedef _Float16 half8_t __attribute__((ext_vector_type(8)));
typedef _Float16 half4_t __attribute__((ext_vector_type(4)));
typedef _Float16 half2_t __attribute__((ext_vector_type(2)));
typedef float f32x4 __attribute__((ext_vector_type(4)));

__device__ __forceinline__ float fdot2f(half2_t a, half2_t b, float c) {
#if __has_builtin(__builtin_amdgcn_fdot2)
  return __builtin_amdgcn_fdot2(a, b, c, false);
#else
  return c + (float)a[0] * (float)b[0] + (float)a[1] * (float)b[1];
#endif
}

__device__ __forceinline__ float dot8(half8_t x, half8_t q) {
  float d = fdot2f((half2_t){x[0], x[1]}, (half2_t){q[0], q[1]}, 0.f);
  d = fdot2f((half2_t){x[2], x[3]}, (half2_t){q[2], q[3]}, d);
  d = fdot2f((half2_t){x[4], x[5]}, (half2_t){q[4], q[5]}, d);
  d = fdot2f((half2_t){x[6], x[7]}, (half2_t){q[6], q[7]}, d);
  return d;
}

// ---------------- t=0: fused prep + bias-LSTM + f32 sweep + x16 mirror ----------------
// (unchanged — at its HBM-compulsory floor ~55 us)
__global__ __launch_bounds__(256) void attn0_kernel(
    const float* __restrict__ x32, const int* __restrict__ batch,
    const float* __restrict__ Wih, const float* __restrict__ Whh,
    const float* __restrict__ bih, const float* __restrict__ bhh,
    _Float16* __restrict__ w16f, int* __restrict__ starts,
    _Float16* __restrict__ x16w, _Float16* __restrict__ q16out) {
  int g = blockIdx.x, tid = threadIdx.x, lane = tid & 63, w = tid >> 6;
  __shared__ int sgs[2];
  __shared__ __align__(16) float h_sh[FF];
  __shared__ __align__(16) float rw[4][FF];
  __shared__ float mw[4], sw[4];

  if (tid < 2) {
    int target = g + tid;
    int lo = 0;
    if (target >= GG) lo = NN;
    else {
      int hi = NN;
      while (lo < hi) {
        int mid = (lo + hi) >> 1;
        if (batch[mid] < target) lo = mid + 1; else hi = mid;
      }
    }
    sgs[tid] = lo;
    starts[g + tid] = lo;
  }

  // w16f prep: blocks 0..511 x 1024 elements = 524288 exactly.
  if (g < 512) {
#pragma unroll
    for (int e = 0; e < 4; ++e) {
      int idx = g * 1024 + e * 256 + tid;
      int n = idx >> 9, k = idx & 511;
      float v = Wih[(size_t)n * 512 + k];
      if (k < FF) v += Whh[(size_t)n * FF + k];
      int dest = ((n >> 4) * 16 + (k >> 5)) * 512 + ((k >> 3) & 3) * 128 +
                 (n & 15) * 8 + (k & 7);
      w16f[dest] = (_Float16)v;
    }
  }

  float bi = bih[tid] + bhh[tid];
  float bg = bih[tid + 512] + bhh[tid + 512];
  float bo = bih[tid + 768] + bhh[tid + 768];
  float si0 = 1.f / (1.f + __expf(-bi));
  float so0 = 1.f / (1.f + __expf(-bo));
  float cv0 = si0 * tanhf(bg);
  float hv0 = so0 * tanhf(cv0);
  q16out[(size_t)g * 512 + tid] = (_Float16)hv0;
  h_sh[tid] = hv0;
  __syncthreads();

  f32x4 qv = *(const f32x4*)&h_sh[4 * lane];
  int s0 = sgs[0], cnt = sgs[1] - sgs[0];

  float m = -INFINITY, ssum = 0.f;
  f32x4 racc = {0.f, 0.f, 0.f, 0.f};
  for (int i0 = w * 4; i0 < cnt; i0 += 16) {
    f32x4 xv[4];
    float d[4];
    bool vld[4];
#pragma unroll
    for (int j = 0; j < 4; ++j) {
      int idx = i0 + j;
      vld[j] = idx < cnt;
      int node = vld[j] ? idx : cnt - 1;
      xv[j] = __builtin_nontemporal_load(
          (const f32x4*)(x32 + (size_t)(s0 + node) * FF + 4 * lane));
    }
#pragma unroll
    for (int j = 0; j < 4; ++j) {
      half4_t hx;
      hx[0] = (_Float16)xv[j][0]; hx[1] = (_Float16)xv[j][1];
      hx[2] = (_Float16)xv[j][2]; hx[3] = (_Float16)xv[j][3];
      int node = vld[j] ? (i0 + j) : cnt - 1;
      *(half4_t*)(x16w + (size_t)(s0 + node) * FF + 4 * lane) = hx;
    }
#pragma unroll
    for (int j = 0; j < 4; ++j)
      d[j] = xv[j][0] * qv[0] + xv[j][1] * qv[1] + xv[j][2] * qv[2] + xv[j][3] * qv[3];
#pragma unroll
    for (int off = 32; off; off >>= 1)
#pragma unroll
      for (int j = 0; j < 4; ++j) d[j] += __shfl_xor(d[j], off);
#pragma unroll
    for (int j = 0; j < 4; ++j) if (!vld[j]) d[j] = -INFINITY;
    float gm = fmaxf(fmaxf(d[0], d[1]), fmaxf(d[2], d[3]));
    if (gm > m) {
      float sc = __expf(m - gm);
      ssum *= sc; racc *= sc;
      m = gm;
    }
#pragma unroll
    for (int j = 0; j < 4; ++j) {
      float p = __expf(d[j] - m);
      ssum += p;
      racc += p * xv[j];
    }
  }

  if (lane == 0) { mw[w] = m; sw[w] = ssum; }
  *(f32x4*)&rw[w][4 * lane] = racc;
  __syncthreads();
  float M = fmaxf(fmaxf(mw[0], mw[1]), fmaxf(mw[2], mw[3]));
  float e0 = (mw[0] == -INFINITY) ? 0.f : __expf(mw[0] - M);
  float e1 = (mw[1] == -INFINITY) ? 0.f : __expf(mw[1] - M);
  float e2 = (mw[2] == -INFINITY) ? 0.f : __expf(mw[2] - M);
  float e3 = (mw[3] == -INFINITY) ? 0.f : __expf(mw[3] - M);
  float denom = sw[0] * e0 + sw[1] * e1 + sw[2] * e2 + sw[3] * e3;
  float rs = rw[0][tid] * e0 + rw[1][tid] * e1 + rw[2][tid] * e2 + rw[3][tid] * e3;
  float r = rs / (denom + 1e-16f);
  if (cnt == 0) r = 0.f;
  q16out[(size_t)g * 512 + FF + tid] = (_Float16)r;
}

// ---------------- t=1..5: GPB=8, 512 thr, NO register cap ----------------
// R14's 2-blocks/CU retried cleanly: plain __launch_bounds__(512) lets VGPR
// land naturally (~70-80) -> 6-8 waves/SIMD from 3-4 resident blocks/CU;
// block A's attn overlaps block B's gemm. (R14's (1024,8) capped VGPR to 32
// -> 383 MB of spill writes -> the experiment was confounded, not refuted.)
// Attention: exactly R12's proven 1-wave-per-graph channel-parallel loop.
__global__ __launch_bounds__(512) void steps_kernel(
    const _Float16* __restrict__ x16, const _Float16* __restrict__ w16f,
    const _Float16* __restrict__ q16a, const int* __restrict__ starts,
    const float* __restrict__ bih, const float* __restrict__ bhh,
    float* __restrict__ qstar) {
  int tid = threadIdx.x, lane = tid & 63, w = tid >> 6;   // w in 0..7
  int lr = lane & 15, kq = lane >> 4;     // gemm quarter coords
  int sl = lane & 31, hf = lane >> 5;     // attn half coords
  int g0 = blockIdx.x * GPB;

  __shared__ _Float16 qs[16][520];        // rows 0..7 = graphs; 8..15 zero pad
  __shared__ float cst[GPB][256];         // LSTM cell state
  __shared__ int sgs[GPB + 1];

  // ---- init ----
  if (tid <= GPB) sgs[tid] = starts[g0 + tid];
#pragma unroll
  for (int e = 0; e < 2; ++e) {           // 16 rows x 64 half8 = 1024 chunks
    int chunk = e * 512 + tid;
    int i = chunk >> 6, c8 = chunk & 63;
    if (i < GPB)
      *(half8_t*)&qs[i][c8 * 8] =
          *(const half8_t*)(q16a + (size_t)(g0 + i) * 512 + c8 * 8);
    else
      *(half8_t*)&qs[i][c8 * 8] = (half8_t){0, 0, 0, 0, 0, 0, 0, 0};
  }
  {
    int f = tid & 255;
    float bi = bih[f] + bhh[f];
    float bg = bih[f + 512] + bhh[f + 512];
    float si0 = 1.f / (1.f + __expf(-bi));
    float cv0 = si0 * tanhf(bg);
    for (int i = tid >> 8; i < GPB; i += 2) cst[i][f] = cv0;
  }
  // pointwise biases: wave w owns f-cols [w*32, w*32+32)
  int fo = w * 32;
  float bi_[2], bf_[2], bg_[2], bo_[2];
#pragma unroll
  for (int fi = 0; fi < 2; ++fi) {
    int f = fo + fi * 16 + lr;
    bi_[fi] = bih[f] + bhh[f];
    bf_[fi] = bih[f + 256] + bhh[f + 256];
    bg_[fi] = bih[f + 512] + bhh[f + 512];
    bo_[fi] = bih[f + 768] + bhh[f + 768];
  }
  __syncthreads();

  for (int t = 1; t < TT; ++t) {
    bool last = (t == TT - 1);

    // ---- gemm: 8 graphs (+8 zero rows) x 32 f-cols x 4 gates, K = 512 ----
    f32x4 acc[2][4];                      // [fi][gate]
#pragma unroll
    for (int fi = 0; fi < 2; ++fi)
#pragma unroll
      for (int gt = 0; gt < 4; ++gt) acc[fi][gt] = (f32x4){0.f, 0.f, 0.f, 0.f};

#pragma unroll 2
    for (int ks = 0; ks < 16; ++ks) {
      int kk = ks * 32 + kq * 8;
      half8_t a = *(const half8_t*)&qs[lr][kk];   // rows >= 8 are zero
#pragma unroll
      for (int fi = 0; fi < 2; ++fi)
#pragma unroll
        for (int gt = 0; gt < 4; ++gt) {
          int nf = gt * 16 + w * 2 + fi;          // W row-tile index
          half8_t b = *(const half8_t*)(
              w16f + ((size_t)nf * 16 + ks) * 512 + lane * 8);
          acc[fi][gt] = __builtin_amdgcn_mfma_f32_16x16x32_f16(a, b, acc[fi][gt], 0, 0, 0);
        }
    }
    __syncthreads();   // all waves done reading qs before h overwrite

    // ---- LSTM pointwise: rows gl < GPB only (kq < 2) ----
#pragma unroll
    for (int fi = 0; fi < 2; ++fi) {
      int f = fo + fi * 16 + lr;
#pragma unroll
      for (int r = 0; r < 4; ++r) {
        int gl = kq * 4 + r;
        if (gl < GPB) {
          float ig = acc[fi][0][r] + bi_[fi];
          float fg = acc[fi][1][r] + bf_[fi];
          float gv = acc[fi][2][r] + bg_[fi];
          float og = acc[fi][3][r] + bo_[fi];
          float si = 1.f / (1.f + __expf(-ig));
          float sf = 1.f / (1.f + __expf(-fg));
          float so = 1.f / (1.f + __expf(-og));
          float cv = sf * cst[gl][f] + si * tanhf(gv);
          float hv = so * tanhf(cv);
          cst[gl][f] = cv;
          qs[gl][f] = (_Float16)hv;
          if (last) qstar[(size_t)(g0 + gl) * 512 + f] = hv;
        }
      }
    }
    __syncthreads();   // full h rows visible before attn reads them

    // ---- attention: wave w owns graph w (R12's proven loop) ----
    {
      int ii = w;
      int s0 = sgs[ii];
      int cnt = sgs[ii + 1] - s0;
      half8_t qh = *(const half8_t*)&qs[ii][sl * 8];

      float m = -INFINITY, ssum = 0.f;
      float racc[8];
#pragma unroll
      for (int e = 0; e < 8; ++e) racc[e] = 0.f;

      for (int i0 = 0; i0 < cnt; i0 += 16) {     // 16 nodes/iter/wave
        half8_t hx[8];
        float d[8];
        bool vld[8];
#pragma unroll
        for (int j = 0; j < 8; ++j) {            // 8 x 1 KB loads in flight
          int idx = i0 + j * 2 + hf;
          vld[j] = idx < cnt;
          int node = vld[j] ? idx : cnt - 1;
          hx[j] = *(const half8_t*)(x16 + (size_t)(s0 + node) * FF + sl * 8);
        }
#pragma unroll
        for (int j = 0; j < 8; ++j) d[j] = dot8(hx[j], qh);
#pragma unroll
        for (int off = 1; off <= 16; off <<= 1)  // 8 interleaved 32-lane trees
#pragma unroll
          for (int j = 0; j < 8; ++j) d[j] += __shfl_xor(d[j], off);
#pragma unroll
        for (int j = 0; j < 8; ++j) if (!vld[j]) d[j] = -INFINITY;
        float gm = -INFINITY;
#pragma unroll
        for (int j = 0; j < 8; ++j) {
          float dother = __shfl_xor(d[j], 32);
          gm = fmaxf(gm, fmaxf(d[j], dother));   // uniform across wave
        }
        if (gm > m) {                            // one rescale per 16 nodes
          float sc = __expf(m - gm);
          ssum *= sc;
#pragma unroll
          for (int e = 0; e < 8; ++e) racc[e] *= sc;
          m = gm;
        }
#pragma unroll
        for (int j = 0; j < 8; ++j) {
          float p = __expf(d[j] - m);            // invalid: exp(-inf)=0
          ssum += p;
#pragma unroll
          for (int e = 0; e < 8; ++e) racc[e] += p * (float)hx[j][e];
        }
      }

      // combine the two 32-lane halves; lane sl holds channels sl*8..+8
      ssum += __shfl_xor(ssum, 32);
#pragma unroll
      for (int e = 0; e < 8; ++e) racc[e] += __shfl_xor(racc[e], 32);
      float inv = 1.0f / (ssum + 1e-16f);

      if (hf == 0) {
        half8_t rh;
        float rv[8];
#pragma unroll
        for (int e = 0; e < 8; ++e) {
          rv[e] = (cnt == 0) ? 0.f : racc[e] * inv;
          rh[e] = (_Float16)rv[e];
        }
        *(half8_t*)&qs[ii][256 + sl * 8] = rh;   // r half for next gemm
        if (last) {
          f32x4 lo = {rv[0], rv[1], rv[2], rv[3]};
          f32x4 hi = {rv[4], rv[5], rv[6], rv[7]};
          *(f32x4*)(qstar + (size_t)(g0 + ii) * 512 + 256 + sl * 8) = lo;
          *(f32x4*)(qstar + (size_t)(g0 + ii) * 512 + 260 + sl * 8) = hi;
        }
      }
    }
    __syncthreads();   // r halves written before next step's gemm reads qs
  }
}

// ---------------- launcher ----------------
extern "C" void kernel_launch(void* const* d_in, const int* in_sizes, int n_in,
                              void* d_out, int out_size, void* d_ws, size_t ws_size,
                              hipStream_t stream) {
  const float* x   = (const float*)d_in[0];
  const int* batch = (const int*)d_in[1];
  // d_in[2] = size (4096), hard-coded
  const float* Wih = (const float*)d_in[3];
  const float* Whh = (const float*)d_in[4];
  const float* bih = (const float*)d_in[5];
  const float* bhh = (const float*)d_in[6];
  float* qstar = (float*)d_out;  // [GG, 512]; steps_kernel t=5 writes it

  uint8_t* p = (uint8_t*)d_ws;
  auto alloc = [&](size_t bytes) {
    uint8_t* q = p;
    p += (bytes + 255) & ~(size_t)255;
    return q;
  };
  _Float16* q16a = (_Float16*)alloc((size_t)GG * 2 * FF * 2);     // 4 MB
  _Float16* w16f = (_Float16*)alloc((size_t)4 * FF * 2 * FF * 2); // 1 MB
  int* starts    = (int*)alloc((size_t)(GG + 1) * 4);
  _Float16* x16  = (_Float16*)alloc((size_t)NN * FF * 2);         // 128 MB

  attn0_kernel<<<GG, 256, 0, stream>>>(
      x, batch, Wih, Whh, bih, bhh, w16f, starts, x16, q16a);

  steps_kernel<<<SBLK, 512, 0, stream>>>(
      x16, w16f, q16a, starts, bih, bhh, qstar);
}

// Round 16
// 238.518 us; speedup vs baseline: 2.2501x; 1.2730x over previous
//
#include <hip/hip_runtime.h>
#include <cstdint>
#include <cstddef>

#define NN 250000   // nodes
#define FF 256      // channels
#define GG 4096     // graphs
#define TT 6        // processing steps
#define GPB 16      // graphs per block in steps_kernel
#define SBLK (GG / GPB)   // 256 blocks = 1/CU (W-stream sweet spot, R15 lesson)

typedef _Float16 half8_t __attribute__((ext_vector_type(8)));
typedef _Float16 half4_t __attribute__((ext_vector_type(4)));
typedef _Float16 half2_t __attribute__((ext_vector_type(2)));
typedef float f32x4 __attribute__((ext_vector_type(4)));

__device__ __forceinline__ float fdot2f(half2_t a, half2_t b, float c) {
#if __has_builtin(__builtin_amdgcn_fdot2)
  return __builtin_amdgcn_fdot2(a, b, c, false);
#else
  return c + (float)a[0] * (float)b[0] + (float)a[1] * (float)b[1];
#endif
}

__device__ __forceinline__ float dot8(half8_t x, half8_t q) {
  float d = fdot2f((half2_t){x[0], x[1]}, (half2_t){q[0], q[1]}, 0.f);
  d = fdot2f((half2_t){x[2], x[3]}, (half2_t){q[2], q[3]}, d);
  d = fdot2f((half2_t){x[4], x[5]}, (half2_t){q[4], q[5]}, d);
  d = fdot2f((half2_t){x[6], x[7]}, (half2_t){q[6], q[7]}, d);
  return d;
}

// ---------------- t=0: fused prep + bias-LSTM + f32 sweep + x16 mirror ----------------
// (unchanged — at its HBM-compulsory floor ~55 us)
__global__ __launch_bounds__(256) void attn0_kernel(
    const float* __restrict__ x32, const int* __restrict__ batch,
    const float* __restrict__ Wih, const float* __restrict__ Whh,
    const float* __restrict__ bih, const float* __restrict__ bhh,
    _Float16* __restrict__ w16f, int* __restrict__ starts,
    _Float16* __restrict__ x16w, _Float16* __restrict__ q16out) {
  int g = blockIdx.x, tid = threadIdx.x, lane = tid & 63, w = tid >> 6;
  __shared__ int sgs[2];
  __shared__ __align__(16) float h_sh[FF];
  __shared__ __align__(16) float rw[4][FF];
  __shared__ float mw[4], sw[4];

  if (tid < 2) {
    int target = g + tid;
    int lo = 0;
    if (target >= GG) lo = NN;
    else {
      int hi = NN;
      while (lo < hi) {
        int mid = (lo + hi) >> 1;
        if (batch[mid] < target) lo = mid + 1; else hi = mid;
      }
    }
    sgs[tid] = lo;
    starts[g + tid] = lo;
  }

  // w16f prep: blocks 0..511 x 1024 elements = 524288 exactly.
  if (g < 512) {
#pragma unroll
    for (int e = 0; e < 4; ++e) {
      int idx = g * 1024 + e * 256 + tid;
      int n = idx >> 9, k = idx & 511;
      float v = Wih[(size_t)n * 512 + k];
      if (k < FF) v += Whh[(size_t)n * FF + k];
      int dest = ((n >> 4) * 16 + (k >> 5)) * 512 + ((k >> 3) & 3) * 128 +
                 (n & 15) * 8 + (k & 7);
      w16f[dest] = (_Float16)v;
    }
  }

  float bi = bih[tid] + bhh[tid];
  float bg = bih[tid + 512] + bhh[tid + 512];
  float bo = bih[tid + 768] + bhh[tid + 768];
  float si0 = 1.f / (1.f + __expf(-bi));
  float so0 = 1.f / (1.f + __expf(-bo));
  float cv0 = si0 * tanhf(bg);
  float hv0 = so0 * tanhf(cv0);
  q16out[(size_t)g * 512 + tid] = (_Float16)hv0;
  h_sh[tid] = hv0;
  __syncthreads();

  f32x4 qv = *(const f32x4*)&h_sh[4 * lane];
  int s0 = sgs[0], cnt = sgs[1] - sgs[0];

  float m = -INFINITY, ssum = 0.f;
  f32x4 racc = {0.f, 0.f, 0.f, 0.f};
  for (int i0 = w * 4; i0 < cnt; i0 += 16) {
    f32x4 xv[4];
    float d[4];
    bool vld[4];
#pragma unroll
    for (int j = 0; j < 4; ++j) {
      int idx = i0 + j;
      vld[j] = idx < cnt;
      int node = vld[j] ? idx : cnt - 1;
      xv[j] = __builtin_nontemporal_load(
          (const f32x4*)(x32 + (size_t)(s0 + node) * FF + 4 * lane));
    }
#pragma unroll
    for (int j = 0; j < 4; ++j) {
      half4_t hx;
      hx[0] = (_Float16)xv[j][0]; hx[1] = (_Float16)xv[j][1];
      hx[2] = (_Float16)xv[j][2]; hx[3] = (_Float16)xv[j][3];
      int node = vld[j] ? (i0 + j) : cnt - 1;
      *(half4_t*)(x16w + (size_t)(s0 + node) * FF + 4 * lane) = hx;
    }
#pragma unroll
    for (int j = 0; j < 4; ++j)
      d[j] = xv[j][0] * qv[0] + xv[j][1] * qv[1] + xv[j][2] * qv[2] + xv[j][3] * qv[3];
#pragma unroll
    for (int off = 32; off; off >>= 1)
#pragma unroll
      for (int j = 0; j < 4; ++j) d[j] += __shfl_xor(d[j], off);
#pragma unroll
    for (int j = 0; j < 4; ++j) if (!vld[j]) d[j] = -INFINITY;
    float gm = fmaxf(fmaxf(d[0], d[1]), fmaxf(d[2], d[3]));
    if (gm > m) {
      float sc = __expf(m - gm);
      ssum *= sc; racc *= sc;
      m = gm;
    }
#pragma unroll
    for (int j = 0; j < 4; ++j) {
      float p = __expf(d[j] - m);
      ssum += p;
      racc += p * xv[j];
    }
  }

  if (lane == 0) { mw[w] = m; sw[w] = ssum; }
  *(f32x4*)&rw[w][4 * lane] = racc;
  __syncthreads();
  float M = fmaxf(fmaxf(mw[0], mw[1]), fmaxf(mw[2], mw[3]));
  float e0 = (mw[0] == -INFINITY) ? 0.f : __expf(mw[0] - M);
  float e1 = (mw[1] == -INFINITY) ? 0.f : __expf(mw[1] - M);
  float e2 = (mw[2] == -INFINITY) ? 0.f : __expf(mw[2] - M);
  float e3 = (mw[3] == -INFINITY) ? 0.f : __expf(mw[3] - M);
  float denom = sw[0] * e0 + sw[1] * e1 + sw[2] * e2 + sw[3] * e3;
  float rs = rw[0][tid] * e0 + rw[1][tid] * e1 + rw[2][tid] * e2 + rw[3][tid] * e3;
  float r = rs / (denom + 1e-16f);
  if (cnt == 0) r = 0.f;
  q16out[(size_t)g * 512 + FF + tid] = (_Float16)r;
}

// ---------------- t=1..5: R12 config restored (best measured: 188 us) ----------------
// 256 blocks x 1024 threads, GPB=16, wave w <-> graph w. Micro-opts vs R12:
// (1) attn loop split into guard-free full iterations + one guarded tail;
// (2) group max via 7 VALU max + ONE cross-half shfl (was 8 shfls) —
// arithmetically identical (max associativity), 7 fewer DS ops per 16 nodes.
__global__ __launch_bounds__(1024, 1) void steps_kernel(
    const _Float16* __restrict__ x16, const _Float16* __restrict__ w16f,
    const _Float16* __restrict__ q16a, const int* __restrict__ starts,
    const float* __restrict__ bih, const float* __restrict__ bhh,
    float* __restrict__ qstar) {
  int tid = threadIdx.x, lane = tid & 63, w = tid >> 6;   // w in 0..15
  int lr = lane & 15, kq = lane >> 4;     // gemm quarter coords
  int sl = lane & 31, hf = lane >> 5;     // attn half coords
  int g0 = blockIdx.x * GPB;

  __shared__ _Float16 qs[GPB][520];       // q_star rows (520 = 512 + 8 pad)
  __shared__ float cst[GPB][256];         // LSTM cell state
  __shared__ int sgs[GPB + 1];

  // ---- init ----
  if (tid <= GPB) sgs[tid] = starts[g0 + tid];
  {
    int i = tid >> 6, c8 = tid & 63;
    *(half8_t*)&qs[i][c8 * 8] =
        *(const half8_t*)(q16a + (size_t)(g0 + i) * 512 + c8 * 8);
  }
  {
    int f = tid & 255;
    float bi = bih[f] + bhh[f];
    float bg = bih[f + 512] + bhh[f + 512];
    float si0 = 1.f / (1.f + __expf(-bi));
    float cv0 = si0 * tanhf(bg);
    for (int i = tid >> 8; i < GPB; i += 4) cst[i][f] = cv0;
  }
  int f = w * 16 + lr;
  float bi_ = bih[f] + bhh[f];
  float bf_ = bih[f + 256] + bhh[f + 256];
  float bg_ = bih[f + 512] + bhh[f + 512];
  float bo_ = bih[f + 768] + bhh[f + 768];
  __syncthreads();

  for (int t = 1; t < TT; ++t) {
    bool last = (t == TT - 1);

    // ---- gemm: 16 graphs x 16 f-cols x 4 gates, K = 512 ----
    f32x4 acc[4];
#pragma unroll
    for (int gt = 0; gt < 4; ++gt) acc[gt] = (f32x4){0.f, 0.f, 0.f, 0.f};

#pragma unroll 4
    for (int ks = 0; ks < 16; ++ks) {
      int kk = ks * 32 + kq * 8;
      half8_t a = *(const half8_t*)&qs[lr][kk];
#pragma unroll
      for (int gt = 0; gt < 4; ++gt) {
        int nf = gt * 16 + w;
        half8_t b = *(const half8_t*)(
            w16f + ((size_t)nf * 16 + ks) * 512 + lane * 8);
        acc[gt] = __builtin_amdgcn_mfma_f32_16x16x32_f16(a, b, acc[gt], 0, 0, 0);
      }
    }
    __syncthreads();

    // ---- LSTM pointwise ----
#pragma unroll
    for (int r = 0; r < 4; ++r) {
      int gl = kq * 4 + r;
      float ig = acc[0][r] + bi_;
      float fg = acc[1][r] + bf_;
      float gv = acc[2][r] + bg_;
      float og = acc[3][r] + bo_;
      float si = 1.f / (1.f + __expf(-ig));
      float sf = 1.f / (1.f + __expf(-fg));
      float so = 1.f / (1.f + __expf(-og));
      float cv = sf * cst[gl][f] + si * tanhf(gv);
      float hv = so * tanhf(cv);
      cst[gl][f] = cv;
      qs[gl][f] = (_Float16)hv;
      if (last) qstar[(size_t)(g0 + gl) * 512 + f] = hv;
    }
    __syncthreads();

    // ---- attention: wave w owns graph w ----
    {
      int ii = w;
      int s0 = sgs[ii];
      int cnt = sgs[ii + 1] - s0;
      half8_t qh = *(const half8_t*)&qs[ii][sl * 8];

      float m = -INFINITY, ssum = 0.f;
      float racc[8];
#pragma unroll
      for (int e = 0; e < 8; ++e) racc[e] = 0.f;

      int nfull = cnt & ~15;               // guard-free 16-node iterations
      for (int i0 = 0; i0 < nfull; i0 += 16) {
        half8_t hx[8];
        float d[8];
#pragma unroll
        for (int j = 0; j < 8; ++j)        // 8 x 1 KB loads in flight
          hx[j] = *(const half8_t*)(
              x16 + (size_t)(s0 + i0 + j * 2 + hf) * FF + sl * 8);
#pragma unroll
        for (int j = 0; j < 8; ++j) d[j] = dot8(hx[j], qh);
#pragma unroll
        for (int off = 1; off <= 16; off <<= 1)
#pragma unroll
          for (int j = 0; j < 8; ++j) d[j] += __shfl_xor(d[j], off);
        float gl_ = d[0];                  // group max: 7 VALU max + 1 shfl
#pragma unroll
        for (int j = 1; j < 8; ++j) gl_ = fmaxf(gl_, d[j]);
        float gm = fmaxf(gl_, __shfl_xor(gl_, 32));
        if (gm > m) {                      // one rescale per 16 nodes
          float sc = __expf(m - gm);
          ssum *= sc;
#pragma unroll
          for (int e = 0; e < 8; ++e) racc[e] *= sc;
          m = gm;
        }
#pragma unroll
        for (int j = 0; j < 8; ++j) {
          float p = __expf(d[j] - m);
          ssum += p;
#pragma unroll
          for (int e = 0; e < 8; ++e) racc[e] += p * (float)hx[j][e];
        }
      }
      if (nfull < cnt) {                   // guarded tail (once)
        half8_t hx[8];
        float d[8];
        bool vld[8];
#pragma unroll
        for (int j = 0; j < 8; ++j) {
          int idx = nfull + j * 2 + hf;
          vld[j] = idx < cnt;
          int node = vld[j] ? idx : cnt - 1;
          hx[j] = *(const half8_t*)(x16 + (size_t)(s0 + node) * FF + sl * 8);
        }
#pragma unroll
        for (int j = 0; j < 8; ++j) d[j] = dot8(hx[j], qh);
#pragma unroll
        for (int off = 1; off <= 16; off <<= 1)
#pragma unroll
          for (int j = 0; j < 8; ++j) d[j] += __shfl_xor(d[j], off);
#pragma unroll
        for (int j = 0; j < 8; ++j) if (!vld[j]) d[j] = -INFINITY;
        float gl_ = d[0];
#pragma unroll
        for (int j = 1; j < 8; ++j) gl_ = fmaxf(gl_, d[j]);
        float gm = fmaxf(gl_, __shfl_xor(gl_, 32));
        if (gm > m) {
          float sc = __expf(m - gm);
          ssum *= sc;
#pragma unroll
          for (int e = 0; e < 8; ++e) racc[e] *= sc;
          m = gm;
        }
#pragma unroll
        for (int j = 0; j < 8; ++j) {
          float p = __expf(d[j] - m);      // invalid: exp(-inf)=0
          ssum += p;
#pragma unroll
          for (int e = 0; e < 8; ++e) racc[e] += p * (float)hx[j][e];
        }
      }

      // combine the two 32-lane halves; lane sl holds channels sl*8..+8
      ssum += __shfl_xor(ssum, 32);
#pragma unroll
      for (int e = 0; e < 8; ++e) racc[e] += __shfl_xor(racc[e], 32);
      float inv = 1.0f / (ssum + 1e-16f);

      if (hf == 0) {
        half8_t rh;
        float rv[8];
#pragma unroll
        for (int e = 0; e < 8; ++e) {
          rv[e] = (cnt == 0) ? 0.f : racc[e] * inv;
          rh[e] = (_Float16)rv[e];
        }
        *(half8_t*)&qs[ii][256 + sl * 8] = rh;   // r half for next gemm
        if (last) {
          f32x4 lo = {rv[0], rv[1], rv[2], rv[3]};
          f32x4 hi = {rv[4], rv[5], rv[6], rv[7]};
          *(f32x4*)(qstar + (size_t)(g0 + ii) * 512 + 256 + sl * 8) = lo;
          *(f32x4*)(qstar + (size_t)(g0 + ii) * 512 + 260 + sl * 8) = hi;
        }
      }
    }
    __syncthreads();
  }
}

// ---------------- launcher ----------------
extern "C" void kernel_launch(void* const* d_in, const int* in_sizes, int n_in,
                              void* d_out, int out_size, void* d_ws, size_t ws_size,
                              hipStream_t stream) {
  const float* x   = (const float*)d_in[0];
  const int* batch = (const int*)d_in[1];
  // d_in[2] = size (4096), hard-coded
  const float* Wih = (const float*)d_in[3];
  const float* Whh = (const float*)d_in[4];
  const float* bih = (const float*)d_in[5];
  const float* bhh = (const float*)d_in[6];
  float* qstar = (float*)d_out;  // [GG, 512]; steps_kernel t=5 writes it

  uint8_t* p = (uint8_t*)d_ws;
  auto alloc = [&](size_t bytes) {
    uint8_t* q = p;
    p += (bytes + 255) & ~(size_t)255;
    return q;
  };
  _Float16* q16a = (_Float16*)alloc((size_t)GG * 2 * FF * 2);     // 4 MB
  _Float16* w16f = (_Float16*)alloc((size_t)4 * FF * 2 * FF * 2); // 1 MB
  int* starts    = (int*)alloc((size_t)(GG + 1) * 4);
  _Float16* x16  = (_Float16*)alloc((size_t)NN * FF * 2);         // 128 MB

  attn0_kernel<<<GG, 256, 0, stream>>>(
      x, batch, Wih, Whh, bih, bhh, w16f, starts, x16, q16a);

  steps_kernel<<<SBLK, 1024, 0, stream>>>(
      x16, w16f, q16a, starts, bih, bhh, qstar);
}